// Round 10
// baseline (220.209 us; speedup 1.0000x reference)
//
#include <hip/hip_runtime.h>

// Problem constants (from reference)
#define VOCAB   35097
#define DDIM    300
#define NWORDS  3000
#define L_SIG   900000          // DDIM * NWORDS
#define NFILT   100
#define NCLS    10

// Tiling. ONE fused kernel: conv phase (r9-proven pk loop, contiguous
// wave-private stores) + device-wide last-block reduce + in-block FC.
// Block = 512 threads = 8 waves = {2 position sub-tiles} x {4 filter-waves}.
#define QQ      28
#define HALFQ   14              // lane packs positions (p, p+HALFQ) per pk op
#define WIN     (QQ + 4)        // 32 floats per lane window
#define NHP     (HALFQ + 4)     // 18 packed float2 window entries
#define SUBPOS  (64 * QQ)       // 1792 positions per sub-tile (per 4-wave set)
#define NBX     252             // ceil(899998 / 3584); block 251 = TAIL
#define ROWS    (NBX * 2)       // 504 partial rows per batch
#define FPG     5               // filters per group (unrolled; static acc)
#define NGRPW   5               // groups per wave -> 25 filters/wave
#define NCHK    8               // row-chunks in the final reduce
#define CHKR    (ROWS / NCHK)   // 63 rows per chunk

typedef __attribute__((ext_vector_type(2))) float f32x2;

__device__ __forceinline__ float relu_(float v) { return fmaxf(v, 0.0f); }

// Packed FP32: 2 FMAs / instruction (r8-proven: issue 70->46us).
__device__ __forceinline__ f32x2 pk_mul(f32x2 a, f32x2 b) {
  f32x2 d;
  asm("v_pk_mul_f32 %0, %1, %2" : "=v"(d) : "v"(a), "v"(b));
  return d;
}
__device__ __forceinline__ f32x2 pk_fma(f32x2 a, f32x2 b, f32x2 c) {
  f32x2 d;
  asm("v_pk_fma_f32 %0, %1, %2, %3" : "=v"(d) : "v"(a), "v"(b), "v"(c));
  return d;
}
__device__ __forceinline__ f32x2 dup2(float w) { f32x2 d; d.x = w; d.y = w; return d; }

// One group: FPG filters x 3 conv sizes over the wave's 64*QQ sub-tile.
// Raw maxes only; bias+ReLU deferred to the reduce phase (monotone).
template<bool TAIL>
__device__ __forceinline__ void run_group(
    const float (&h)[WIN], const f32x2 (&hp)[NHP], int t0, int f0, int lane,
    const float* __restrict__ w1, const float* __restrict__ w2,
    const float* __restrict__ w3,
    float* __restrict__ pslot)   // 15 consecutive floats (wave-private)
{
  int n3 = QQ, n4 = QQ, n5 = QQ;
  if (TAIL) {
    n3 = min(max(899998 - t0, 0), QQ);   // conv3 valid t <= 899997
    n4 = min(max(899997 - t0, 0), QQ);   // conv4 valid t <= 899996
    n5 = min(max(899996 - t0, 0), QQ);   // conv5 valid t <= 899995
  }
  const float NEG = -__builtin_huge_valf();

  float a3[FPG], a4[FPG], a5[FPG];       // static indexing only (full unroll)

  #pragma unroll
  for (int j = 0; j < FPG; ++j) {
    const int fu = __builtin_amdgcn_readfirstlane(f0 + j);
    const float a0 = w1[fu*3+0], a1 = w1[fu*3+1], a2 = w1[fu*3+2];
    const float c0 = w2[fu*4+0], c1 = w2[fu*4+1], c2 = w2[fu*4+2], c3 = w2[fu*4+3];
    const float e0 = w3[fu*5+0], e1 = w3[fu*5+1], e2 = w3[fu*5+2], e3 = w3[fu*5+3], e4 = w3[fu*5+4];

    float m3a = NEG, m3b = NEG, m4a = NEG, m4b = NEG, m5a = NEG, m5b = NEG;

    if (!TAIL) {
      const f32x2 pa0 = dup2(a0), pa1 = dup2(a1), pa2 = dup2(a2);
      const f32x2 pc0 = dup2(c0), pc1 = dup2(c1), pc2 = dup2(c2), pc3 = dup2(c3);
      const f32x2 pe0 = dup2(e0), pe1 = dup2(e1), pe2 = dup2(e2), pe3 = dup2(e3), pe4 = dup2(e4);

      #pragma unroll
      for (int p = 0; p < HALFQ; ++p) {
        // Each pk op computes the conv at positions p (lo) and p+HALFQ (hi).
        f32x2 t3 = pk_mul(pa2, hp[p+2]);
        t3 = pk_fma(pa1, hp[p+1], t3);
        t3 = pk_fma(pa0, hp[p+0], t3);
        f32x2 t4 = pk_mul(pc3, hp[p+3]);
        t4 = pk_fma(pc2, hp[p+2], t4);
        t4 = pk_fma(pc1, hp[p+1], t4);
        t4 = pk_fma(pc0, hp[p+0], t4);
        f32x2 t5 = pk_mul(pe4, hp[p+4]);
        t5 = pk_fma(pe3, hp[p+3], t5);
        t5 = pk_fma(pe2, hp[p+2], t5);
        t5 = pk_fma(pe1, hp[p+1], t5);
        t5 = pk_fma(pe0, hp[p+0], t5);
        // fmaxf(fmaxf(m, x), y) fuses to v_max3_f32; alternate accumulators.
        if (p & 1) {
          m3b = fmaxf(fmaxf(m3b, t3.x), t3.y);
          m4b = fmaxf(fmaxf(m4b, t4.x), t4.y);
          m5b = fmaxf(fmaxf(m5b, t5.x), t5.y);
        } else {
          m3a = fmaxf(fmaxf(m3a, t3.x), t3.y);
          m4a = fmaxf(fmaxf(m4a, t4.x), t4.y);
          m5a = fmaxf(fmaxf(m5a, t5.x), t5.y);
        }
      }
    } else {
      #pragma unroll
      for (int p = 0; p < QQ; ++p) {
        float v3 = fmaf(a0, h[p], fmaf(a1, h[p+1], a2 * h[p+2]));
        float v4 = fmaf(c0, h[p], fmaf(c1, h[p+1], fmaf(c2, h[p+2], c3 * h[p+3])));
        float v5 = fmaf(e0, h[p], fmaf(e1, h[p+1], fmaf(e2, h[p+2], fmaf(e3, h[p+3], e4 * h[p+4]))));
        if (p < n3) { if (p & 1) m3b = fmaxf(m3b, v3); else m3a = fmaxf(m3a, v3); }
        if (p < n4) { if (p & 1) m4b = fmaxf(m4b, v4); else m4a = fmaxf(m4a, v4); }
        if (p < n5) { if (p & 1) m5b = fmaxf(m5b, v5); else m5a = fmaxf(m5a, v5); }
      }
    }
    a3[j] = fmaxf(m3a, m3b);
    a4[j] = fmaxf(m4a, m4b);
    a5[j] = fmaxf(m5a, m5b);
  }

  // ONE batched wave reduction per group: 15 independent 6-level chains.
  #pragma unroll
  for (int s = 1; s < 64; s <<= 1) {
    #pragma unroll
    for (int j = 0; j < FPG; ++j) {
      a3[j] = fmaxf(a3[j], __shfl_xor(a3[j], s));
      a4[j] = fmaxf(a4[j], __shfl_xor(a4[j], s));
      a5[j] = fmaxf(a5[j], __shfl_xor(a5[j], s));
    }
  }

  // Wave-private CONTIGUOUS slot (r9-proven: WRITE stays ~1.2 MB, no
  // cross-XCD false sharing).
  if (lane == 0) {
    #pragma unroll
    for (int j = 0; j < FPG; ++j) {
      pslot[j]      = a3[j];
      pslot[5 + j]  = a4[j];
      pslot[10 + j] = a5[j];
    }
  }
}

__global__ __launch_bounds__(512, 4) void cnn_fused_kernel(
    const int* __restrict__ x, const float* __restrict__ emb,
    const float* __restrict__ w1, const float* __restrict__ b1,
    const float* __restrict__ w2, const float* __restrict__ b2,
    const float* __restrict__ w3, const float* __restrict__ b3,
    const float* __restrict__ fcw, const float* __restrict__ fcb,
    float* __restrict__ partial,      // [2][ROWS][300]
    unsigned int* __restrict__ counter,
    float* __restrict__ out)
{
  const int tid   = threadIdx.x;
  const int lane  = tid & 63;
  const int wave  = tid >> 6;          // 0..7
  const int w4    = wave & 3;          // filter-wave (25 filters each)
  const int half  = wave >> 2;         // position sub-tile 0/1
  const int batch = blockIdx.y;
  const int row   = blockIdx.x * 2 + half;
  const int sub0  = blockIdx.x * (2 * SUBPOS) + half * SUBPOS;
  const int t0    = sub0 + lane * QQ;
  const int fbase = w4 * (FPG * NGRPW);

  // ---- conv phase ----
  // Gather the signal window [t0, t0+WIN) directly from emb.
  // t0 % 4 == 0 and DDIM % 4 == 0 -> float4-aligned; window spans <= 2 rows.
  // OOB lanes clamp (TAIL masks their contributions; their maxes stay -inf,
  // absorbed by the final column max).
  float h[WIN];
  {
    int w0 = t0 / DDIM;
    int d0 = t0 - w0 * DDIM;                 // multiple of 4
    int wa = min(w0, NWORDS - 1);
    int wb = min(w0 + 1, NWORDS - 1);
    int xa = x[batch * NWORDS + wa];
    int xb = x[batch * NWORDS + wb];
    const float4* rowA = (const float4*)(emb + (size_t)xa * DDIM) + (d0 >> 2);
    const float4* rowB = (const float4*)(emb + (size_t)xb * DDIM);
    const int nf4 = (DDIM - d0) >> 2;        // float4s remaining in word A
    #pragma unroll
    for (int i = 0; i < WIN / 4; ++i) {
      const float4* src = (i < nf4) ? (rowA + i) : (rowB + (i - nf4));
      float4 v = *src;
      h[4*i+0] = v.x; h[4*i+1] = v.y; h[4*i+2] = v.z; h[4*i+3] = v.w;
    }
  }

  // Pack distant-position pairs for v_pk ops: hp[k] = {h[k], h[k+HALFQ]}.
  f32x2 hp[NHP];
  #pragma unroll
  for (int k = 0; k < NHP; ++k) { f32x2 t; t.x = h[k]; t.y = h[k + HALFQ]; hp[k] = t; }

  float* pwave = partial + ((size_t)batch * ROWS + row) * 300 + w4 * 75;

  const bool tail = (sub0 + SUBPOS + 4) > L_SIG;   // only block 251 (both halves)
  if (tail) {
    #pragma unroll 1
    for (int g = 0; g < NGRPW; ++g)
      run_group<true >(h, hp, t0, fbase + g * FPG, lane, w1, w2, w3, pwave + g * 15);
  } else {
    #pragma unroll 1
    for (int g = 0; g < NGRPW; ++g)
      run_group<false>(h, hp, t0, fbase + g * FPG, lane, w1, w2, w3, pwave + g * 15);
  }

  // ---- device-wide completion count (canonical threadfence pattern) ----
  __shared__ int s_last;
  __threadfence();                 // make this block's partial stores visible
  __syncthreads();
  if (tid == 0) {
    unsigned int old = atomicAdd(counter, 1u);
    s_last = (old == (unsigned int)(NBX * 2 - 1));
  }
  __syncthreads();
  if (!s_last) return;
  __threadfence();                 // acquire: all 504 blocks' partials visible

  // ---- last block: reduce partial over rows (float4, 1200 parallel tasks) ----
  __shared__ float4 chunkres[150][NCHK];   // 150 f4-columns x 8 row-chunks
  __shared__ float  s_feats[2][3 * NFILT];

  for (int task = tid; task < 2 * 75 * NCHK; task += 512) {
    const int chunk = task / 150;          // consecutive tid -> consecutive c4
    const int rem   = task % 150;          //   -> coalesced float4 reads
    const int bi    = rem / 75;
    const int c4    = rem % 75;
    const float* base = partial + ((size_t)bi * ROWS + chunk * CHKR) * 300 + c4 * 4;
    float4 m; m.x = m.y = m.z = m.w = -__builtin_huge_valf();
    #pragma unroll 9
    for (int r = 0; r < CHKR; ++r) {
      float4 v = *(const float4*)(base + (size_t)r * 300);
      m.x = fmaxf(m.x, v.x); m.y = fmaxf(m.y, v.y);
      m.z = fmaxf(m.z, v.z); m.w = fmaxf(m.w, v.w);
    }
    chunkres[rem][chunk] = m;
  }
  __syncthreads();

  if (tid < 150) {
    float4 m = chunkres[tid][0];
    #pragma unroll
    for (int k = 1; k < NCHK; ++k) {
      float4 v = chunkres[tid][k];
      m.x = fmaxf(m.x, v.x); m.y = fmaxf(m.y, v.y);
      m.z = fmaxf(m.z, v.z); m.w = fmaxf(m.w, v.w);
    }
    const int bi = tid / 75, c4 = tid % 75;
    #pragma unroll
    for (int e = 0; e < 4; ++e) {
      const float ve = (e == 0) ? m.x : (e == 1) ? m.y : (e == 2) ? m.z : m.w;
      const int p = c4 * 4 + e;
      // Decode p -> (conv, filter): p = w4*75 + g*15 + conv*5 + j
      const int pw = p / 75, r2 = p % 75, g = r2 / 15, q = r2 % 15;
      const int conv = q / 5, j = q % 5;
      const int f = pw * 25 + g * 5 + j;
      const float bias = (conv == 0) ? b1[f] : (conv == 1) ? b2[f] : b3[f];
      s_feats[bi][conv * NFILT + f] = relu_(ve + bias);
    }
  }
  __syncthreads();

  // ---- FC: 20 outputs over 8 waves ----
  for (int o = wave; o < 2 * NCLS; o += 8) {
    const int ob = o / NCLS, oc = o % NCLS;
    float s = 0.0f;
    for (int k = lane; k < 3 * NFILT; k += 64)
      s += s_feats[ob][k] * fcw[oc * 3 * NFILT + k];
    #pragma unroll
    for (int sft = 1; sft < 64; sft <<= 1) s += __shfl_xor(s, sft);
    if (lane == 0) out[ob * NCLS + oc] = s + fcb[oc];
  }
}

extern "C" void kernel_launch(void* const* d_in, const int* in_sizes, int n_in,
                              void* d_out, int out_size, void* d_ws, size_t ws_size,
                              hipStream_t stream)
{
  const int*   x   = (const int*)  d_in[0];
  const float* emb = (const float*)d_in[1];
  const float* w1  = (const float*)d_in[2];
  const float* b1  = (const float*)d_in[3];
  const float* w2  = (const float*)d_in[4];
  const float* b2  = (const float*)d_in[5];
  const float* w3  = (const float*)d_in[6];
  const float* b3  = (const float*)d_in[7];
  const float* fcw = (const float*)d_in[8];
  const float* fcb = (const float*)d_in[9];
  float* out = (float*)d_out;

  // Workspace: partial [2][ROWS][300] floats (1.21 MB), then the counter.
  float* partial = (float*)d_ws;
  unsigned int* counter = (unsigned int*)(partial + (size_t)2 * ROWS * 300);

  hipMemsetAsync(counter, 0, sizeof(unsigned int), stream);

  dim3 grid(NBX, 2);
  cnn_fused_kernel<<<grid, 512, 0, stream>>>(x, emb, w1, b1, w2, b2, w3, b3,
                                             fcw, fcb, partial, counter, out);
}

// Round 11
// 169.383 us; speedup vs baseline: 1.3001x; 1.3001x over previous
//
#include <hip/hip_runtime.h>

// Problem constants (from reference)
#define VOCAB   35097
#define DDIM    300
#define NWORDS  3000
#define L_SIG   900000          // DDIM * NWORDS
#define NFILT   100
#define NCLS    10

// Tiling: r9-proven conv (pk inner loop, contiguous wave-private stores)
// + two-stage parallel tree reduce (r10 showed single-block reduce tail and
// per-block device fences cost ~75us; r9's 2-block reduce cost ~38us).
#define QQ      28
#define HALFQ   14              // lane packs positions (p, p+HALFQ) per pk op
#define WIN     (QQ + 4)        // 32 floats per lane window
#define NHP     (HALFQ + 4)     // 18 packed float2 window entries
#define BLK_POS (64 * QQ)       // 1792 positions per block
#define NBLKA   503             // ceil(899998 / 1792); block 502 = TAIL
#define FPG     5               // filters per group (unrolled; static acc)
#define NGRPW   5               // groups per wave -> 25 filters/wave
#define NCHKA   63              // stage-A chunks; 63*8 = 504 >= 503 rows

typedef __attribute__((ext_vector_type(2))) float f32x2;

__device__ __forceinline__ float relu_(float v) { return fmaxf(v, 0.0f); }

// Packed FP32: 2 FMAs / instruction (r8-proven: issue 70->46us).
__device__ __forceinline__ f32x2 pk_mul(f32x2 a, f32x2 b) {
  f32x2 d;
  asm("v_pk_mul_f32 %0, %1, %2" : "=v"(d) : "v"(a), "v"(b));
  return d;
}
__device__ __forceinline__ f32x2 pk_fma(f32x2 a, f32x2 b, f32x2 c) {
  f32x2 d;
  asm("v_pk_fma_f32 %0, %1, %2, %3" : "=v"(d) : "v"(a), "v"(b), "v"(c));
  return d;
}
__device__ __forceinline__ f32x2 dup2(float w) { f32x2 d; d.x = w; d.y = w; return d; }

// One group: FPG filters x 3 conv sizes over the wave's 64*QQ tile.
// Raw maxes only; bias+ReLU deferred to reduce stage B (monotone).
template<bool TAIL>
__device__ __forceinline__ void run_group(
    const float (&h)[WIN], const f32x2 (&hp)[NHP], int t0, int f0, int lane,
    const float* __restrict__ w1, const float* __restrict__ w2,
    const float* __restrict__ w3,
    float* __restrict__ pslot)   // 15 consecutive floats (wave-private)
{
  int n3 = QQ, n4 = QQ, n5 = QQ;
  if (TAIL) {
    n3 = min(max(899998 - t0, 0), QQ);   // conv3 valid t <= 899997
    n4 = min(max(899997 - t0, 0), QQ);   // conv4 valid t <= 899996
    n5 = min(max(899996 - t0, 0), QQ);   // conv5 valid t <= 899995
  }
  const float NEG = -__builtin_huge_valf();

  float a3[FPG], a4[FPG], a5[FPG];       // static indexing only (full unroll)

  #pragma unroll
  for (int j = 0; j < FPG; ++j) {
    const int fu = __builtin_amdgcn_readfirstlane(f0 + j);
    const float a0 = w1[fu*3+0], a1 = w1[fu*3+1], a2 = w1[fu*3+2];
    const float c0 = w2[fu*4+0], c1 = w2[fu*4+1], c2 = w2[fu*4+2], c3 = w2[fu*4+3];
    const float e0 = w3[fu*5+0], e1 = w3[fu*5+1], e2 = w3[fu*5+2], e3 = w3[fu*5+3], e4 = w3[fu*5+4];

    float m3a = NEG, m3b = NEG, m4a = NEG, m4b = NEG, m5a = NEG, m5b = NEG;

    if (!TAIL) {
      const f32x2 pa0 = dup2(a0), pa1 = dup2(a1), pa2 = dup2(a2);
      const f32x2 pc0 = dup2(c0), pc1 = dup2(c1), pc2 = dup2(c2), pc3 = dup2(c3);
      const f32x2 pe0 = dup2(e0), pe1 = dup2(e1), pe2 = dup2(e2), pe3 = dup2(e3), pe4 = dup2(e4);

      #pragma unroll
      for (int p = 0; p < HALFQ; ++p) {
        // Each pk op computes the conv at positions p (lo) and p+HALFQ (hi).
        f32x2 t3 = pk_mul(pa2, hp[p+2]);
        t3 = pk_fma(pa1, hp[p+1], t3);
        t3 = pk_fma(pa0, hp[p+0], t3);
        f32x2 t4 = pk_mul(pc3, hp[p+3]);
        t4 = pk_fma(pc2, hp[p+2], t4);
        t4 = pk_fma(pc1, hp[p+1], t4);
        t4 = pk_fma(pc0, hp[p+0], t4);
        f32x2 t5 = pk_mul(pe4, hp[p+4]);
        t5 = pk_fma(pe3, hp[p+3], t5);
        t5 = pk_fma(pe2, hp[p+2], t5);
        t5 = pk_fma(pe1, hp[p+1], t5);
        t5 = pk_fma(pe0, hp[p+0], t5);
        // fmaxf(fmaxf(m, x), y) fuses to v_max3_f32; alternate accumulators.
        if (p & 1) {
          m3b = fmaxf(fmaxf(m3b, t3.x), t3.y);
          m4b = fmaxf(fmaxf(m4b, t4.x), t4.y);
          m5b = fmaxf(fmaxf(m5b, t5.x), t5.y);
        } else {
          m3a = fmaxf(fmaxf(m3a, t3.x), t3.y);
          m4a = fmaxf(fmaxf(m4a, t4.x), t4.y);
          m5a = fmaxf(fmaxf(m5a, t5.x), t5.y);
        }
      }
    } else {
      #pragma unroll
      for (int p = 0; p < QQ; ++p) {
        float v3 = fmaf(a0, h[p], fmaf(a1, h[p+1], a2 * h[p+2]));
        float v4 = fmaf(c0, h[p], fmaf(c1, h[p+1], fmaf(c2, h[p+2], c3 * h[p+3])));
        float v5 = fmaf(e0, h[p], fmaf(e1, h[p+1], fmaf(e2, h[p+2], fmaf(e3, h[p+3], e4 * h[p+4]))));
        if (p < n3) { if (p & 1) m3b = fmaxf(m3b, v3); else m3a = fmaxf(m3a, v3); }
        if (p < n4) { if (p & 1) m4b = fmaxf(m4b, v4); else m4a = fmaxf(m4a, v4); }
        if (p < n5) { if (p & 1) m5b = fmaxf(m5b, v5); else m5a = fmaxf(m5a, v5); }
      }
    }
    a3[j] = fmaxf(m3a, m3b);
    a4[j] = fmaxf(m4a, m4b);
    a5[j] = fmaxf(m5a, m5b);
  }

  // ONE batched wave reduction per group: 15 independent 6-level chains.
  #pragma unroll
  for (int s = 1; s < 64; s <<= 1) {
    #pragma unroll
    for (int j = 0; j < FPG; ++j) {
      a3[j] = fmaxf(a3[j], __shfl_xor(a3[j], s));
      a4[j] = fmaxf(a4[j], __shfl_xor(a4[j], s));
      a5[j] = fmaxf(a5[j], __shfl_xor(a5[j], s));
    }
  }

  // Wave-private CONTIGUOUS slot (r9-proven: WRITE ~1.2 MB, no cross-XCD
  // false sharing; r8's strided layout cost +32us).
  if (lane == 0) {
    #pragma unroll
    for (int j = 0; j < FPG; ++j) {
      pslot[j]      = a3[j];
      pslot[5 + j]  = a4[j];
      pslot[10 + j] = a5[j];
    }
  }
}

__global__ __launch_bounds__(256, 4) void conv_max_kernel(
    const int* __restrict__ x, const float* __restrict__ emb,
    const float* __restrict__ w1, const float* __restrict__ w2,
    const float* __restrict__ w3,
    float* __restrict__ partial)      // [2][NBLKA][300]
{
  const int lane  = threadIdx.x & 63;
  const int wave  = threadIdx.x >> 6;
  const int batch = blockIdx.y;
  const int t0_blk = blockIdx.x * BLK_POS;
  const int t0     = t0_blk + lane * QQ;
  const int fbase  = wave * (FPG * NGRPW);  // 25 filters per wave

  // Gather the signal window [t0, t0+WIN) directly from emb.
  // t0 % 4 == 0 and DDIM % 4 == 0 -> float4-aligned; window spans <= 2 rows.
  // OOB lanes clamp (TAIL masks them; their maxes stay -inf, absorbed).
  float h[WIN];
  {
    int w0 = t0 / DDIM;
    int d0 = t0 - w0 * DDIM;                 // multiple of 4
    int wa = min(w0, NWORDS - 1);
    int wb = min(w0 + 1, NWORDS - 1);
    int xa = x[batch * NWORDS + wa];
    int xb = x[batch * NWORDS + wb];
    const float4* rowA = (const float4*)(emb + (size_t)xa * DDIM) + (d0 >> 2);
    const float4* rowB = (const float4*)(emb + (size_t)xb * DDIM);
    const int nf4 = (DDIM - d0) >> 2;        // float4s remaining in word A
    #pragma unroll
    for (int i = 0; i < WIN / 4; ++i) {
      const float4* src = (i < nf4) ? (rowA + i) : (rowB + (i - nf4));
      float4 v = *src;
      h[4*i+0] = v.x; h[4*i+1] = v.y; h[4*i+2] = v.z; h[4*i+3] = v.w;
    }
  }

  // Pack distant-position pairs for v_pk ops: hp[k] = {h[k], h[k+HALFQ]}.
  f32x2 hp[NHP];
  #pragma unroll
  for (int k = 0; k < NHP; ++k) { f32x2 t; t.x = h[k]; t.y = h[k + HALFQ]; hp[k] = t; }

  // Wave-private contiguous slot: p = wave*75 + g*15 + (conv*5 + j).
  float* pwave = partial + ((size_t)batch * NBLKA + blockIdx.x) * 300 + wave * 75;

  const bool tail = (t0_blk + BLK_POS + 4) > L_SIG;   // only block 502
  if (tail) {
    #pragma unroll 1
    for (int g = 0; g < NGRPW; ++g)
      run_group<true >(h, hp, t0, fbase + g * FPG, lane, w1, w2, w3, pwave + g * 15);
  } else {
    #pragma unroll 1
    for (int g = 0; g < NGRPW; ++g)
      run_group<false>(h, hp, t0, fbase + g * FPG, lane, w1, w2, w3, pwave + g * 15);
  }
}

// Stage A: block (chunk, b) maxes 8 rows of partial -> out2[b][chunk][300].
// Reads coalesced across p (consecutive threads, consecutive addresses);
// 126 blocks run in parallel on 126 CUs.
__global__ __launch_bounds__(320) void reduceA_kernel(
    const float* __restrict__ partial, float* __restrict__ out2)
{
  const int chunk = blockIdx.x;         // 0..62
  const int b     = blockIdx.y;         // 0..1
  const int p     = threadIdx.x;        // 0..319; p<300 active
  if (p >= 300) return;

  const int r0 = chunk * 8;
  const int nr = min(8, NBLKA - r0);    // 8, except last chunk = 7
  const float* base = partial + ((size_t)b * NBLKA + r0) * 300 + p;
  float m = -__builtin_huge_valf();
  #pragma unroll
  for (int r = 0; r < 8; ++r)
    if (r < nr) m = fmaxf(m, base[(size_t)r * 300]);
  out2[((size_t)b * NCHKA + chunk) * 300 + p] = m;
}

// Stage B: thread p maxes the 63 chunk-values (coalesced across p), applies
// bias+ReLU, writes feats[b][300] in reference concat order (c3|c4|c5).
__global__ __launch_bounds__(320) void reduceB_kernel(
    const float* __restrict__ out2,
    const float* __restrict__ b1, const float* __restrict__ b2,
    const float* __restrict__ b3,
    float* __restrict__ feats)
{
  const int b = blockIdx.x;             // 0..1
  const int p = threadIdx.x;            // 0..319; p<300 active
  if (p >= 300) return;

  const float* col = out2 + (size_t)b * NCHKA * 300 + p;
  float m = -__builtin_huge_valf();
  #pragma unroll
  for (int r = 0; r < NCHKA; ++r)
    m = fmaxf(m, col[(size_t)r * 300]);

  // Decode p -> (conv, filter): p = wave*75 + g*15 + conv*5 + j
  const int wv = p / 75, r2 = p % 75, g = r2 / 15, q = r2 % 15;
  const int conv = q / 5, j = q % 5;
  const int f = wv * 25 + g * 5 + j;
  const float bias = (conv == 0) ? b1[f] : (conv == 1) ? b2[f] : b3[f];
  feats[b * 300 + conv * NFILT + f] = relu_(m + bias);
}

// out[b][c] = sum_k feats[b][k] * fc_w[c][k] + fc_b[c]
__global__ void fc_kernel(const float* __restrict__ feats,
                          const float* __restrict__ fcw,
                          const float* __restrict__ fcb,
                          float* __restrict__ out)
{
  const int b = blockIdx.x / NCLS;
  const int c = blockIdx.x % NCLS;
  const int lane = threadIdx.x;
  float s = 0.0f;
  for (int k = lane; k < 3 * NFILT; k += 64)
    s += feats[b * 3 * NFILT + k] * fcw[c * 3 * NFILT + k];
  #pragma unroll
  for (int k = 1; k < 64; k <<= 1) s += __shfl_xor(s, k);
  if (lane == 0) out[b * NCLS + c] = s + fcb[c];
}

extern "C" void kernel_launch(void* const* d_in, const int* in_sizes, int n_in,
                              void* d_out, int out_size, void* d_ws, size_t ws_size,
                              hipStream_t stream)
{
  const int*   x   = (const int*)  d_in[0];
  const float* emb = (const float*)d_in[1];
  const float* w1  = (const float*)d_in[2];
  const float* b1  = (const float*)d_in[3];
  const float* w2  = (const float*)d_in[4];
  const float* b2  = (const float*)d_in[5];
  const float* w3  = (const float*)d_in[6];
  const float* b3  = (const float*)d_in[7];
  const float* fcw = (const float*)d_in[8];
  const float* fcb = (const float*)d_in[9];
  float* out = (float*)d_out;

  // Workspace: partial [2][NBLKA][300], out2 [2][NCHKA][300], feats [2][300].
  // Every slot read downstream is written upstream in-stream -> no memset.
  float* partial = (float*)d_ws;                        // 1.207 MB
  float* out2    = partial + (size_t)2 * NBLKA * 300;   // +151 KB
  float* feats   = out2 + (size_t)2 * NCHKA * 300;      // +2.4 KB

  dim3 gconv(NBLKA, 2);
  conv_max_kernel<<<gconv, 256, 0, stream>>>(x, emb, w1, w2, w3, partial);
  dim3 gredA(NCHKA, 2);
  reduceA_kernel<<<gredA, 320, 0, stream>>>(partial, out2);
  reduceB_kernel<<<2, 320, 0, stream>>>(out2, b1, b2, b3, feats);
  fc_kernel<<<2 * NCLS, 64, 0, stream>>>(feats, fcw, fcb, out);
}